// Round 2
// baseline (1500.810 us; speedup 1.0000x reference)
//
#include <hip/hip_runtime.h>

#define TX 32
#define TY 16
#define RAD 5
#define HY (TY + 2*RAD)    // 26 staged rows
#define XP 48              // staged cols: img cols [32*bx-8, 32*bx+40), 16B-aligned
#define HP 32              // hbuf pitch (conflict-free for c=lane&31 column reads)

// Gaussian K=11 sigma=1.5, normalized (sum = 1 - 2e-8)
#define KW0 0.00102838f
#define KW1 0.00759875f
#define KW2 0.03600077f
#define KW3 0.10936069f
#define KW4 0.21300554f
#define KW5 0.26601172f

__device__ __forceinline__ float fast_sigmoid(float v) {
    return __builtin_amdgcn_rcpf(1.0f + __expf(-v));
}

__global__ __launch_bounds__(256, 6) void ssim_fused_kernel(
    const float* __restrict__ xlog, const float* __restrict__ yin,
    float* __restrict__ ws, float* __restrict__ out,
    int nblocks, float invN)
{
    const float kw[11] = {KW0,KW1,KW2,KW3,KW4,KW5,KW4,KW3,KW2,KW1,KW0};

    __shared__ __align__(16) float xs[HY][XP];
    __shared__ __align__(16) float ys[HY][XP];
    __shared__ __align__(16) float hbuf[5][HY][HP];

    const int tid = threadIdx.x;
    const int bx = blockIdx.x, by = blockIdx.y;
    const long long base = (long long)blockIdx.z * (512LL * 512LL);
    const int row0 = by * TY - RAD;     // first staged img row
    const int colb = bx * TX - 8;       // first staged img col (aligned to 16B)

    // ---- Stage 1: global -> LDS (sigmoid on x) ----
    if (bx >= 1 && bx <= 14 && by >= 1 && by <= 30) {
        // interior: no bounds checks, float4 everywhere
        for (int i = tid; i < HY * 12; i += 256) {
            int r = i / 12;
            int c4 = (i - r * 12) << 2;
            long long idx = base + (long long)(row0 + r) * 512 + colb + c4;
            float4 xv = *(const float4*)(xlog + idx);
            float4 yv = *(const float4*)(yin + idx);
            float4 s;
            s.x = fast_sigmoid(xv.x);
            s.y = fast_sigmoid(xv.y);
            s.z = fast_sigmoid(xv.z);
            s.w = fast_sigmoid(xv.w);
            *(float4*)&xs[r][c4] = s;
            *(float4*)&ys[r][c4] = yv;
        }
    } else {
        // edge: scalar with zero padding
        for (int i = tid; i < HY * XP; i += 256) {
            int r = i / XP;
            int c = i - r * XP;
            int gr = row0 + r, gc = colb + c;
            float xv = 0.f, yv = 0.f;
            if (gr >= 0 && gr < 512 && gc >= 0 && gc < 512) {
                long long idx = base + (long long)gr * 512 + gc;
                xv = fast_sigmoid(xlog[idx]);
                yv = yin[idx];
            }
            xs[r][c] = xv;
            ys[r][c] = yv;
        }
    }
    __syncthreads();

    // ---- Stage 2: horizontal 11-tap, sliding window, 4 outputs/thread ----
    // output col c (img col 32bx+c) needs xs cols j = c+3 .. c+13
    if (tid < HY * 8) {
        const int r  = tid >> 3;
        const int c0 = (tid & 7) << 2;
        float xv[20], yv[20];
        #pragma unroll
        for (int q = 0; q < 5; ++q) {
            *(float4*)&xv[4*q] = *(const float4*)&xs[r][c0 + 4*q];
            *(float4*)&yv[4*q] = *(const float4*)&ys[r][c0 + 4*q];
        }
        float sx[4], sy[4], sxx[4], syy[4], sxy[4];
        #pragma unroll
        for (int c = 0; c < 4; ++c) { sx[c]=sy[c]=sxx[c]=syy[c]=sxy[c]=0.f; }
        #pragma unroll
        for (int j = 0; j < 11; ++j) {
            const float w = kw[j];
            #pragma unroll
            for (int c = 0; c < 4; ++c) {
                float a = xv[c + 3 + j];
                float b = yv[c + 3 + j];
                float ta = w * a, tb = w * b;
                sx[c]  += ta;      sy[c]  += tb;
                sxx[c] += ta * a;  syy[c] += tb * b;  sxy[c] += ta * b;
            }
        }
        *(float4*)&hbuf[0][r][c0] = make_float4(sx[0], sx[1], sx[2], sx[3]);
        *(float4*)&hbuf[1][r][c0] = make_float4(sy[0], sy[1], sy[2], sy[3]);
        *(float4*)&hbuf[2][r][c0] = make_float4(sxx[0],sxx[1],sxx[2],sxx[3]);
        *(float4*)&hbuf[3][r][c0] = make_float4(syy[0],syy[1],syy[2],syy[3]);
        *(float4*)&hbuf[4][r][c0] = make_float4(sxy[0],sxy[1],sxy[2],sxy[3]);
    }
    __syncthreads();

    // ---- Stage 3: vertical 11-tap, 2 outputs/thread + SSIM ----
    const int c  = tid & 31;
    const int r0 = (tid >> 5) << 1;   // output rows r0, r0+1
    float a0[5], a1[5];
    #pragma unroll
    for (int ch = 0; ch < 5; ++ch) { a0[ch] = 0.f; a1[ch] = 0.f; }
    #pragma unroll
    for (int j = 0; j < 12; ++j) {
        float v[5];
        #pragma unroll
        for (int ch = 0; ch < 5; ++ch) v[ch] = hbuf[ch][r0 + j][c];
        if (j < 11) {
            const float w = kw[j];
            #pragma unroll
            for (int ch = 0; ch < 5; ++ch) a0[ch] += w * v[ch];
        }
        if (j >= 1) {
            const float w = kw[j - 1];
            #pragma unroll
            for (int ch = 0; ch < 5; ++ch) a1[ch] += w * v[ch];
        }
    }

    float local = 0.f;
    #pragma unroll
    for (int o = 0; o < 2; ++o) {
        const float* u = (o == 0) ? a0 : a1;
        float ux = u[0], uy = u[1], uxx = u[2], uyy = u[3], uxy = u[4];
        float vx  = uxx - ux * ux;
        float vy  = uyy - uy * uy;
        float vxy = uxy - ux * uy;
        float num = (2.f * ux * uy + 1e-4f) * (2.f * vxy + 9e-4f);
        float den = (ux * ux + uy * uy + 1e-4f) * (vx + vy + 9e-4f);
        local += num * __builtin_amdgcn_rcpf(den + 1e-12f);
    }

    // ---- Stage 4: block reduce -> atomic; last block finalizes ----
    #pragma unroll
    for (int off = 32; off > 0; off >>= 1)
        local += __shfl_down(local, off, 64);
    __shared__ float wsum[4];
    if ((tid & 63) == 0) wsum[tid >> 6] = local;
    __syncthreads();
    if (tid == 0) {
        float s = wsum[0] + wsum[1] + wsum[2] + wsum[3];
        atomicAdd(&ws[0], s);
        __threadfence();
        unsigned int* cnt = (unsigned int*)(ws + 1);
        unsigned int old = atomicAdd(cnt, 1u);
        if (old == (unsigned int)nblocks - 1u) {
            float tot = atomicAdd(&ws[0], 0.0f);   // device-scope read
            out[0] = 1.0f - tot * invN;
        }
    }
}

extern "C" void kernel_launch(void* const* d_in, const int* in_sizes, int n_in,
                              void* d_out, int out_size, void* d_ws, size_t ws_size,
                              hipStream_t stream) {
    const float* xlog = (const float*)d_in[0];
    const float* yin  = (const float*)d_in[1];
    float* out = (float*)d_out;
    float* ws  = (float*)d_ws;

    const int Himg = 512, Wimg = 512;
    const int B = in_sizes[0] / (Himg * Wimg);   // 64

    // ws[0] = accum (float), ws[1] = block counter (uint). Re-poisoned to 0xAA
    // before every timed call -> zero them here.
    hipMemsetAsync(ws, 0, 2 * sizeof(float), stream);

    dim3 grid(Wimg / TX, Himg / TY, B);
    int nblocks = grid.x * grid.y * grid.z;
    float invN = 1.0f / ((float)B * Himg * Wimg);
    ssim_fused_kernel<<<grid, 256, 0, stream>>>(xlog, yin, ws, out, nblocks, invN);
}

// Round 4
// 1323.199 us; speedup vs baseline: 1.1342x; 1.1342x over previous
//
#include <hip/hip_runtime.h>

#define TX 32
#define TY 16
#define RAD 5
#define HY (TY + 2*RAD)    // 26 staged rows
#define XP 48              // staged cols: img cols [32*bx-8, 32*bx+40), 16B-aligned
#define HP 32              // hbuf pitch

// Gaussian K=11 sigma=1.5, normalized
#define KW0 0.00102838f
#define KW1 0.00759875f
#define KW2 0.03600077f
#define KW3 0.10936069f
#define KW4 0.21300554f
#define KW5 0.26601172f

__device__ __forceinline__ float fast_sigmoid(float v) {
    return __builtin_amdgcn_rcpf(1.0f + __expf(-v));
}

__device__ __forceinline__ float ssim_px(float ux, float uy, float uxx,
                                         float uyy, float uxy) {
    float vx  = uxx - ux * ux;
    float vy  = uyy - uy * uy;
    float vxy = uxy - ux * uy;
    float num = (2.f * ux * uy + 1e-4f) * (2.f * vxy + 9e-4f);
    float den = (ux * ux + uy * uy + 1e-4f) * (vx + vy + 9e-4f);
    return num * __builtin_amdgcn_rcpf(den + 1e-12f);
}

__global__ __launch_bounds__(256, 4) void ssim_fused_kernel(
    const float* __restrict__ xlog, const float* __restrict__ yin,
    float* __restrict__ ws, float* __restrict__ out,
    int nblocks, float invN)
{
    const float kw[11] = {KW0,KW1,KW2,KW3,KW4,KW5,KW4,KW3,KW2,KW1,KW0};

    __shared__ __align__(16) float xs[HY][XP];
    __shared__ __align__(16) float ys[HY][XP];
    __shared__ __align__(16) float hbuf[5][HY][HP];

    const int tid = threadIdx.x;
    const int bx = blockIdx.x, by = blockIdx.y;
    const long long base = (long long)blockIdx.z * (512LL * 512LL);
    const int row0 = by * TY - RAD;     // first staged img row
    const int colb = bx * TX - 8;       // first staged img col (16B aligned)

    // ---- Stage 1: global -> LDS (sigmoid on x) ----
    if (bx >= 1 && bx <= 14 && by >= 1 && by <= 30) {
        // interior: no bounds checks, float4 everywhere
        for (int i = tid; i < HY * 12; i += 256) {
            int r = i / 12;
            int c4 = (i - r * 12) << 2;
            long long idx = base + (long long)(row0 + r) * 512 + colb + c4;
            float4 xv = *(const float4*)(xlog + idx);
            float4 yv = *(const float4*)(yin + idx);
            float4 s;
            s.x = fast_sigmoid(xv.x);
            s.y = fast_sigmoid(xv.y);
            s.z = fast_sigmoid(xv.z);
            s.w = fast_sigmoid(xv.w);
            *(float4*)&xs[r][c4] = s;
            *(float4*)&ys[r][c4] = yv;
        }
    } else {
        // edge: scalar with zero padding
        for (int i = tid; i < HY * XP; i += 256) {
            int r = i / XP;
            int c = i - r * XP;
            int gr = row0 + r, gc = colb + c;
            float xv = 0.f, yv = 0.f;
            if (gr >= 0 && gr < 512 && gc >= 0 && gc < 512) {
                long long idx = base + (long long)gr * 512 + gc;
                xv = fast_sigmoid(xlog[idx]);
                yv = yin[idx];
            }
            xs[r][c] = xv;
            ys[r][c] = yv;
        }
    }
    __syncthreads();

    // ---- Stage 2: horizontal 11-tap, sliding window, 4 outputs/thread ----
    // output col c (img col 32bx+c) needs xs cols j = c+3 .. c+13
    if (tid < HY * 8) {
        const int r  = tid >> 3;
        const int c0 = (tid & 7) << 2;
        float xv[20], yv[20];
        #pragma unroll
        for (int q = 0; q < 5; ++q) {
            *(float4*)&xv[4*q] = *(const float4*)&xs[r][c0 + 4*q];
            *(float4*)&yv[4*q] = *(const float4*)&ys[r][c0 + 4*q];
        }
        float sx[4], sy[4], sxx[4], syy[4], sxy[4];
        #pragma unroll
        for (int c = 0; c < 4; ++c) { sx[c]=sy[c]=sxx[c]=syy[c]=sxy[c]=0.f; }
        #pragma unroll
        for (int j = 0; j < 11; ++j) {
            const float w = kw[j];
            #pragma unroll
            for (int c = 0; c < 4; ++c) {
                float a = xv[c + 3 + j];
                float b = yv[c + 3 + j];
                float ta = w * a, tb = w * b;
                sx[c]  += ta;      sy[c]  += tb;
                sxx[c] += ta * a;  syy[c] += tb * b;  sxy[c] += ta * b;
            }
        }
        *(float4*)&hbuf[0][r][c0] = make_float4(sx[0], sx[1], sx[2], sx[3]);
        *(float4*)&hbuf[1][r][c0] = make_float4(sy[0], sy[1], sy[2], sy[3]);
        *(float4*)&hbuf[2][r][c0] = make_float4(sxx[0],sxx[1],sxx[2],sxx[3]);
        *(float4*)&hbuf[3][r][c0] = make_float4(syy[0],syy[1],syy[2],syy[3]);
        *(float4*)&hbuf[4][r][c0] = make_float4(sxy[0],sxy[1],sxy[2],sxy[3]);
    }
    __syncthreads();

    // ---- Stage 3: vertical 11-tap, 2 outputs/thread + SSIM ----
    // All accumulators are NAMED scalars: no arrays, no address-taken locals.
    const int c  = tid & 31;
    const int r0 = (tid >> 5) << 1;   // output rows r0, r0+1
    float ux0=0.f, uy0=0.f, uxx0=0.f, uyy0=0.f, uxy0=0.f;
    float ux1=0.f, uy1=0.f, uxx1=0.f, uyy1=0.f, uxy1=0.f;
    #pragma unroll
    for (int j = 0; j < 12; ++j) {
        float v0 = hbuf[0][r0 + j][c];
        float v1 = hbuf[1][r0 + j][c];
        float v2 = hbuf[2][r0 + j][c];
        float v3 = hbuf[3][r0 + j][c];
        float v4 = hbuf[4][r0 + j][c];
        if (j < 11) {
            const float w = kw[j];
            ux0 += w*v0; uy0 += w*v1; uxx0 += w*v2; uyy0 += w*v3; uxy0 += w*v4;
        }
        if (j >= 1) {
            const float w = kw[j - 1];
            ux1 += w*v0; uy1 += w*v1; uxx1 += w*v2; uyy1 += w*v3; uxy1 += w*v4;
        }
    }

    float local = ssim_px(ux0, uy0, uxx0, uyy0, uxy0)
                + ssim_px(ux1, uy1, uxx1, uyy1, uxy1);

    // ---- Stage 4: block reduce -> atomic; last block finalizes ----
    #pragma unroll
    for (int off = 32; off > 0; off >>= 1)
        local += __shfl_down(local, off, 64);
    __shared__ float wsum[4];
    if ((tid & 63) == 0) wsum[tid >> 6] = local;
    __syncthreads();
    if (tid == 0) {
        float s = wsum[0] + wsum[1] + wsum[2] + wsum[3];
        atomicAdd(&ws[0], s);
        __threadfence();
        unsigned int* cnt = (unsigned int*)(ws + 1);
        unsigned int old = atomicAdd(cnt, 1u);
        if (old == (unsigned int)nblocks - 1u) {
            float tot = atomicAdd(&ws[0], 0.0f);   // device-scope read
            out[0] = 1.0f - tot * invN;
        }
    }
}

extern "C" void kernel_launch(void* const* d_in, const int* in_sizes, int n_in,
                              void* d_out, int out_size, void* d_ws, size_t ws_size,
                              hipStream_t stream) {
    const float* xlog = (const float*)d_in[0];
    const float* yin  = (const float*)d_in[1];
    float* out = (float*)d_out;
    float* ws  = (float*)d_ws;

    const int Himg = 512, Wimg = 512;
    const int B = in_sizes[0] / (Himg * Wimg);   // 64

    // ws[0] = accum (float), ws[1] = block counter (uint); re-poisoned to 0xAA
    // before every timed call -> zero them here.
    hipMemsetAsync(ws, 0, 2 * sizeof(float), stream);

    dim3 grid(Wimg / TX, Himg / TY, B);
    int nblocks = grid.x * grid.y * grid.z;
    float invN = 1.0f / ((float)B * Himg * Wimg);
    ssim_fused_kernel<<<grid, 256, 0, stream>>>(xlog, yin, ws, out, nblocks, invN);
}

// Round 5
// 256.813 us; speedup vs baseline: 5.8440x; 5.1524x over previous
//
#include <hip/hip_runtime.h>

#define TX 32
#define TY 16
#define RAD 5
#define HY (TY + 2*RAD)    // 26 staged rows
#define XP 48              // staged cols: img cols [32*bx-8, 32*bx+40), 16B-aligned
#define HP 36              // hbuf pitch: 144 B rows -> +4 bank rotation/row (conflict-free)

// Gaussian K=11 sigma=1.5, normalized
#define KW0 0.00102838f
#define KW1 0.00759875f
#define KW2 0.03600077f
#define KW3 0.10936069f
#define KW4 0.21300554f
#define KW5 0.26601172f

__device__ __forceinline__ float fast_sigmoid(float v) {
    return __builtin_amdgcn_rcpf(1.0f + __expf(-v));
}

__device__ __forceinline__ float ssim_px(float ux, float uy, float uxx,
                                         float uyy, float uxy) {
    float vx  = uxx - ux * ux;
    float vy  = uyy - uy * uy;
    float vxy = uxy - ux * uy;
    float num = (2.f * ux * uy + 1e-4f) * (2.f * vxy + 9e-4f);
    float den = (ux * ux + uy * uy + 1e-4f) * (vx + vy + 9e-4f);
    return num * __builtin_amdgcn_rcpf(den + 1e-12f);
}

template <bool ATOMIC_FALLBACK>
__global__ __launch_bounds__(256, 4) void ssim_fused_kernel(
    const float* __restrict__ xlog, const float* __restrict__ yin,
    float* __restrict__ ws, float* __restrict__ out,
    int nblocks, float invN)
{
    const float kw[11] = {KW0,KW1,KW2,KW3,KW4,KW5,KW4,KW3,KW2,KW1,KW0};

    __shared__ __align__(16) float xs[HY][XP];
    __shared__ __align__(16) float ys[HY][XP];
    __shared__ __align__(16) float hbuf[5][HY][HP];

    const int tid = threadIdx.x;
    const int bx = blockIdx.x, by = blockIdx.y;
    const long long base = (long long)blockIdx.z * (512LL * 512LL);
    const int row0 = by * TY - RAD;     // first staged img row
    const int colb = bx * TX - 8;       // first staged img col (16B aligned)

    // ---- Stage 1: global -> LDS (sigmoid on x) ----
    if (bx >= 1 && bx <= 14 && by >= 1 && by <= 30) {
        // interior: no bounds checks, float4 everywhere
        for (int i = tid; i < HY * 12; i += 256) {
            int r = i / 12;
            int c4 = (i - r * 12) << 2;
            long long idx = base + (long long)(row0 + r) * 512 + colb + c4;
            float4 xv = *(const float4*)(xlog + idx);
            float4 yv = *(const float4*)(yin + idx);
            float4 s;
            s.x = fast_sigmoid(xv.x);
            s.y = fast_sigmoid(xv.y);
            s.z = fast_sigmoid(xv.z);
            s.w = fast_sigmoid(xv.w);
            *(float4*)&xs[r][c4] = s;
            *(float4*)&ys[r][c4] = yv;
        }
    } else {
        // edge: scalar with zero padding
        for (int i = tid; i < HY * XP; i += 256) {
            int r = i / XP;
            int c = i - r * XP;
            int gr = row0 + r, gc = colb + c;
            float xv = 0.f, yv = 0.f;
            if (gr >= 0 && gr < 512 && gc >= 0 && gc < 512) {
                long long idx = base + (long long)gr * 512 + gc;
                xv = fast_sigmoid(xlog[idx]);
                yv = yin[idx];
            }
            xs[r][c] = xv;
            ys[r][c] = yv;
        }
    }
    __syncthreads();

    // ---- Stage 2: horizontal 11-tap, sliding window, 4 outputs/thread ----
    // output col c (img col 32bx+c) needs xs cols j = c+3 .. c+13
    if (tid < HY * 8) {
        const int r  = tid >> 3;
        const int c0 = (tid & 7) << 2;
        float xv[20], yv[20];
        #pragma unroll
        for (int q = 0; q < 5; ++q) {
            *(float4*)&xv[4*q] = *(const float4*)&xs[r][c0 + 4*q];
            *(float4*)&yv[4*q] = *(const float4*)&ys[r][c0 + 4*q];
        }
        float sx[4], sy[4], sxx[4], syy[4], sxy[4];
        #pragma unroll
        for (int c = 0; c < 4; ++c) { sx[c]=sy[c]=sxx[c]=syy[c]=sxy[c]=0.f; }
        #pragma unroll
        for (int j = 0; j < 11; ++j) {
            const float w = kw[j];
            #pragma unroll
            for (int c = 0; c < 4; ++c) {
                float a = xv[c + 3 + j];
                float b = yv[c + 3 + j];
                float ta = w * a, tb = w * b;
                sx[c]  += ta;      sy[c]  += tb;
                sxx[c] += ta * a;  syy[c] += tb * b;  sxy[c] += ta * b;
            }
        }
        *(float4*)&hbuf[0][r][c0] = make_float4(sx[0], sx[1], sx[2], sx[3]);
        *(float4*)&hbuf[1][r][c0] = make_float4(sy[0], sy[1], sy[2], sy[3]);
        *(float4*)&hbuf[2][r][c0] = make_float4(sxx[0],sxx[1],sxx[2],sxx[3]);
        *(float4*)&hbuf[3][r][c0] = make_float4(syy[0],syy[1],syy[2],syy[3]);
        *(float4*)&hbuf[4][r][c0] = make_float4(sxy[0],sxy[1],sxy[2],sxy[3]);
    }
    __syncthreads();

    // ---- Stage 3: vertical 11-tap, 2 outputs/thread + SSIM ----
    const int c  = tid & 31;
    const int r0 = (tid >> 5) << 1;   // output rows r0, r0+1
    float ux0=0.f, uy0=0.f, uxx0=0.f, uyy0=0.f, uxy0=0.f;
    float ux1=0.f, uy1=0.f, uxx1=0.f, uyy1=0.f, uxy1=0.f;
    #pragma unroll
    for (int j = 0; j < 12; ++j) {
        float v0 = hbuf[0][r0 + j][c];
        float v1 = hbuf[1][r0 + j][c];
        float v2 = hbuf[2][r0 + j][c];
        float v3 = hbuf[3][r0 + j][c];
        float v4 = hbuf[4][r0 + j][c];
        if (j < 11) {
            const float w = kw[j];
            ux0 += w*v0; uy0 += w*v1; uxx0 += w*v2; uyy0 += w*v3; uxy0 += w*v4;
        }
        if (j >= 1) {
            const float w = kw[j - 1];
            ux1 += w*v0; uy1 += w*v1; uxx1 += w*v2; uyy1 += w*v3; uxy1 += w*v4;
        }
    }

    float local = ssim_px(ux0, uy0, uxx0, uyy0, uxy0)
                + ssim_px(ux1, uy1, uxx1, uyy1, uxy1);

    // ---- Stage 4: block reduce -> per-block slot (NO same-address atomics) ----
    #pragma unroll
    for (int off = 32; off > 0; off >>= 1)
        local += __shfl_down(local, off, 64);
    __shared__ float wsum[4];
    if ((tid & 63) == 0) wsum[tid >> 6] = local;
    __syncthreads();
    if (tid == 0) {
        float s = wsum[0] + wsum[1] + wsum[2] + wsum[3];
        if (ATOMIC_FALLBACK) {
            atomicAdd(&ws[0], s);
            __threadfence();
            unsigned int* cnt = (unsigned int*)(ws + 1);
            unsigned int old = atomicAdd(cnt, 1u);
            if (old == (unsigned int)nblocks - 1u) {
                float tot = atomicAdd(&ws[0], 0.0f);
                out[0] = 1.0f - tot * invN;
            }
        } else {
            int bid = bx + (int)gridDim.x * (by + (int)gridDim.y * blockIdx.z);
            ws[bid] = s;
        }
    }
}

__global__ __launch_bounds__(256) void reduce_finalize_kernel(
    const float* __restrict__ ws, float* __restrict__ out,
    int n4, float invN)
{
    // n4 = number of float4 elements; single block.
    const int tid = threadIdx.x;
    float s = 0.f;
    for (int i = tid; i < n4; i += 256) {
        float4 v = ((const float4*)ws)[i];
        s += (v.x + v.y) + (v.z + v.w);
    }
    #pragma unroll
    for (int off = 32; off > 0; off >>= 1)
        s += __shfl_down(s, off, 64);
    __shared__ float wsum[4];
    if ((tid & 63) == 0) wsum[tid >> 6] = s;
    __syncthreads();
    if (tid == 0)
        out[0] = 1.0f - (wsum[0] + wsum[1] + wsum[2] + wsum[3]) * invN;
}

extern "C" void kernel_launch(void* const* d_in, const int* in_sizes, int n_in,
                              void* d_out, int out_size, void* d_ws, size_t ws_size,
                              hipStream_t stream) {
    const float* xlog = (const float*)d_in[0];
    const float* yin  = (const float*)d_in[1];
    float* out = (float*)d_out;
    float* ws  = (float*)d_ws;

    const int Himg = 512, Wimg = 512;
    const int B = in_sizes[0] / (Himg * Wimg);   // 64

    dim3 grid(Wimg / TX, Himg / TY, B);          // 16 x 32 x 64 = 32768 blocks
    int nblocks = grid.x * grid.y * grid.z;
    float invN = 1.0f / ((float)B * Himg * Wimg);

    if (ws_size >= (size_t)nblocks * sizeof(float)) {
        // Main path: per-block partials (every slot overwritten -> no memset),
        // then a single-block reduction kernel.
        ssim_fused_kernel<false><<<grid, 256, 0, stream>>>(
            xlog, yin, ws, out, nblocks, invN);
        reduce_finalize_kernel<<<1, 256, 0, stream>>>(ws, out, nblocks / 4, invN);
    } else {
        // Fallback (tiny ws): old atomic path. ws re-poisoned to 0xAA -> zero it.
        hipMemsetAsync(ws, 0, 2 * sizeof(float), stream);
        ssim_fused_kernel<true><<<grid, 256, 0, stream>>>(
            xlog, yin, ws, out, nblocks, invN);
    }
}